// Round 1
// baseline (6969.450 us; speedup 1.0000x reference)
//
#include <hip/hip_runtime.h>
#include <hip/hip_fp16.h>

typedef _Float16 half8 __attribute__((ext_vector_type(8)));
typedef _Float16 half4v __attribute__((ext_vector_type(4)));
typedef float floatx4 __attribute__((ext_vector_type(4)));

// Problem dims (fixed for this problem)
constexpr int BN = 128;    // batch
constexpr int T  = 1024;   // time steps
constexpr int D  = 512;    // input dim
constexpr int H  = 512;    // hidden dim
constexpr int M  = BN * T; // GEMM rows = 131072

// Workspace layout (bytes)
constexpr size_t OFF_CNT  = 0;                    // cnt[8][1024] u32 = 32 KB
constexpr size_t OFF_HEX  = 65536;                // h_ex[2][8][16][512] f16 = 256 KB
constexpr size_t OFF_WIHT = OFF_HEX + 262144;     // W_ih^T f16 = 512 KB
constexpr size_t OFF_WHHT = OFF_WIHT + 524288;    // W_hh^T f16 = 512 KB
constexpr size_t OFF_XP   = 2097152;              // xp f16 = 128 MB

__device__ __forceinline__ float fast_tanh(float x) {
    // tanh(x) = 1 - 2/(exp(2x)+1); saturates correctly for |x| large (inf -> 1)
    float e = __expf(2.0f * x);
    return 1.0f - 2.0f / (e + 1.0f);
}

// ---------------------------------------------------------------------------
// Prep: transpose 512x512 fp32 -> fp16 (row-major [n][k] = W[k][n])
// blockIdx.z: 0 = W_ih, 1 = W_hh
// ---------------------------------------------------------------------------
__global__ __launch_bounds__(256) void prep_transpose(
    const float* __restrict__ Wih, const float* __restrict__ Whh,
    _Float16* __restrict__ WihT, _Float16* __restrict__ WhhT)
{
    __shared__ float tile[32][33];
    const float* src = (blockIdx.z == 0) ? Wih : Whh;
    _Float16* dst    = (blockIdx.z == 0) ? WihT : WhhT;
    const int tx = threadIdx.x & 31;
    const int ty = threadIdx.x >> 5;           // 0..7
    const int kbase = blockIdx.y * 32;
    const int nbase = blockIdx.x * 32;
    for (int r = 0; r < 4; ++r)
        tile[ty + r * 8][tx] = src[(size_t)(kbase + ty + r * 8) * 512 + nbase + tx];
    __syncthreads();
    for (int r = 0; r < 4; ++r)
        dst[(size_t)(nbase + ty + r * 8) * 512 + kbase + tx] =
            (_Float16)tile[tx][ty + r * 8];
}

// ---------------------------------------------------------------------------
// Prep: zero the publish counters (8 groups x 1024 steps)
// ---------------------------------------------------------------------------
__global__ __launch_bounds__(256) void zero_cnt(unsigned int* __restrict__ cnt)
{
    int i = blockIdx.x * 256 + threadIdx.x;
    if (i < 8 * 1024) cnt[i] = 0u;
}

// ---------------------------------------------------------------------------
// Phase 1: xp[m][n] = x[m][:] @ W_ih  (fp16 MFMA, fp32 accum, fp16 out)
// grid: (N/128=4, M/128=1024), block 256 (4 waves, 2x2 of 64x64)
// ---------------------------------------------------------------------------
__global__ __launch_bounds__(256) void xp_gemm(
    const float* __restrict__ x, const _Float16* __restrict__ WT,
    _Float16* __restrict__ xp)
{
    __shared__ _Float16 As[128][40];   // [m][k] pad 32->40 (2-way conflicts free)
    __shared__ _Float16 Bs[128][40];   // [n][k]
    const int tid  = threadIdx.x;
    const int lane = tid & 63;
    const int w    = tid >> 6;
    const int wm   = w & 1, wn = w >> 1;
    const int l15  = lane & 15, q = lane >> 4;
    const size_t mbase = (size_t)blockIdx.y * 128;
    const int    nbase = blockIdx.x * 128;

    floatx4 acc[4][4];
    for (int i = 0; i < 4; ++i)
        for (int j = 0; j < 4; ++j)
            acc[i][j] = (floatx4){0.f, 0.f, 0.f, 0.f};

    for (int kt = 0; kt < 16; ++kt) {
        const int k0 = kt * 32;
        // stage A (x fp32 -> fp16): 128 rows x 32 k
        {
            const int k4 = (tid & 7) * 4;
            const int row0 = tid >> 3;   // 0..31
            for (int r = 0; r < 4; ++r) {
                const int row = row0 + r * 32;
                const float4 v = *(const float4*)&x[(mbase + row) * D + k0 + k4];
                half4v hv;
                hv[0] = (_Float16)v.x; hv[1] = (_Float16)v.y;
                hv[2] = (_Float16)v.z; hv[3] = (_Float16)v.w;
                *(half4v*)&As[row][k4] = hv;
            }
        }
        // stage B (W^T fp16): 128 n-rows x 32 k
        {
            const int k8 = (tid & 3) * 8;
            const int n0 = tid >> 2;     // 0..63
            for (int r = 0; r < 2; ++r) {
                const int n = n0 + r * 64;
                *(half8*)&Bs[n][k8] =
                    *(const half8*)&WT[(size_t)(nbase + n) * D + k0 + k8];
            }
        }
        __syncthreads();
        half8 a[4], b[4];
        for (int i = 0; i < 4; ++i)
            a[i] = *(const half8*)&As[wm * 64 + i * 16 + l15][q * 8];
        for (int j = 0; j < 4; ++j)
            b[j] = *(const half8*)&Bs[wn * 64 + j * 16 + l15][q * 8];
        for (int i = 0; i < 4; ++i)
            for (int j = 0; j < 4; ++j)
                acc[i][j] = __builtin_amdgcn_mfma_f32_16x16x32_f16(
                    a[i], b[j], acc[i][j], 0, 0, 0);
        __syncthreads();
    }
    // epilogue: C/D layout col=lane&15, row=q*4+reg
    for (int i = 0; i < 4; ++i)
        for (int j = 0; j < 4; ++j)
            for (int r = 0; r < 4; ++r) {
                const size_t row = mbase + wm * 64 + i * 16 + q * 4 + r;
                const int    col = nbase + wn * 64 + j * 16 + l15;
                xp[row * H + col] = (_Float16)acc[i][j][r];
            }
}

// ---------------------------------------------------------------------------
// Phase 2: sequential scan. 64 WGs: group g (16 batch rows) x slice s (64 cols).
// Waves split K (128 each), W_hh^T fragments pinned in registers.
// h exchanged via global double buffer + per-step publish counters.
// ---------------------------------------------------------------------------
__global__ __launch_bounds__(256) void rnn_scan(
    const _Float16* __restrict__ xp, const _Float16* __restrict__ WhhT,
    const float* __restrict__ bias, _Float16* __restrict__ h_ex,
    unsigned int* __restrict__ cnt, float* __restrict__ out)
{
    const int bx = blockIdx.x;
    const int g = bx & 7;        // row group (XCD-affine under %8 round-robin)
    const int s = bx >> 3;       // column slice
    const int tid = threadIdx.x, lane = tid & 63, w = tid >> 6;
    const int l15 = lane & 15, q = lane >> 4;

    __shared__ float red[16][64][4];  // [w*4+i][lane][reg] = 16 KB

    // W_hh^T fragments: n-tile i (cols s*64+i*16), k-tile c (k = w*128+c*32)
    half8 wf[4][4];
    for (int i = 0; i < 4; ++i)
        for (int c = 0; c < 4; ++c)
            wf[i][c] = *(const half8*)&WhhT[
                (size_t)(s * 64 + i * 16 + l15) * H + w * 128 + c * 32 + q * 8];

    // epilogue: wave w owns n-tile w (16 cols), rows m = q*4+r
    const int jcol = s * 64 + w * 16 + l15;
    const float bj = bias[jcol];
    const size_t HEXG = (size_t)16 * H;          // per-group slab
    const size_t HEXB = (size_t)8 * HEXG;        // per-buffer slab

    // t = 0: h1 = tanh(xp[:,0,:] + b)   (h0 = 0, no matmul)
    {
        _Float16* hout = h_ex + 1 * HEXB + g * HEXG;
        for (int r = 0; r < 4; ++r) {
            const int m = q * 4 + r;
            const int b = g * 16 + m;
            float v = (float)xp[((size_t)b * T + 0) * H + jcol] + bj;
            hout[(size_t)m * H + jcol] = (_Float16)fast_tanh(v);
        }
        __syncthreads();
        if (tid == 0)
            __hip_atomic_fetch_add(&cnt[g * 1024 + 1], 1u,
                                   __ATOMIC_RELEASE, __HIP_MEMORY_SCOPE_AGENT);
    }

    for (int t = 1; t < T; ++t) {
        // prefetch xp[:,t,:] (independent of h — hides latency behind the poll)
        float xpv[4];
        for (int r = 0; r < 4; ++r) {
            const int b = g * 16 + q * 4 + r;
            xpv[r] = (float)xp[((size_t)b * T + t) * H + jcol];
        }
        // wait for all 8 slices of h_t
        while (__hip_atomic_load(&cnt[g * 1024 + t],
                                 __ATOMIC_ACQUIRE, __HIP_MEMORY_SCOPE_AGENT) < 8u)
            __builtin_amdgcn_s_sleep(1);

        const _Float16* hbuf = h_ex + (size_t)(t & 1) * HEXB + g * HEXG;
        half8 a[4];
        for (int c = 0; c < 4; ++c)
            a[c] = *(const half8*)&hbuf[(size_t)l15 * H + w * 128 + c * 32 + q * 8];

        floatx4 acc[4];
        for (int i = 0; i < 4; ++i) acc[i] = (floatx4){0.f, 0.f, 0.f, 0.f};
        for (int c = 0; c < 4; ++c)
            for (int i = 0; i < 4; ++i)
                acc[i] = __builtin_amdgcn_mfma_f32_16x16x32_f16(
                    a[c], wf[i][c], acc[i], 0, 0, 0);

        // cross-wave K reduction via LDS
        for (int i = 0; i < 4; ++i)
            *(floatx4*)&red[w * 4 + i][lane][0] = acc[i];
        __syncthreads();
        floatx4 sum = *(const floatx4*)&red[0 * 4 + w][lane][0];
        for (int w2 = 1; w2 < 4; ++w2) {
            floatx4 p = *(const floatx4*)&red[w2 * 4 + w][lane][0];
            sum = sum + p;
        }

        if (t < T - 1) {
            _Float16* hout = h_ex + (size_t)((t + 1) & 1) * HEXB + g * HEXG;
            for (int r = 0; r < 4; ++r) {
                const int m = q * 4 + r;
                float v = sum[r] + xpv[r] + bj;
                hout[(size_t)m * H + jcol] = (_Float16)fast_tanh(v);
            }
            __syncthreads();   // all waves' stores drained (vmcnt) before publish
            if (tid == 0)
                __hip_atomic_fetch_add(&cnt[g * 1024 + t + 1], 1u,
                                       __ATOMIC_RELEASE, __HIP_MEMORY_SCOPE_AGENT);
        } else {
            for (int r = 0; r < 4; ++r) {
                const int b = g * 16 + q * 4 + r;
                float v = sum[r] + xpv[r] + bj;
                out[(size_t)b * H + jcol] = fast_tanh(v);
            }
        }
    }
}

// ---------------------------------------------------------------------------
extern "C" void kernel_launch(void* const* d_in, const int* in_sizes, int n_in,
                              void* d_out, int out_size, void* d_ws, size_t ws_size,
                              hipStream_t stream)
{
    const float* x   = (const float*)d_in[0];
    const float* Wih = (const float*)d_in[1];
    const float* Whh = (const float*)d_in[2];
    const float* b   = (const float*)d_in[3];
    float* out = (float*)d_out;

    char* ws = (char*)d_ws;
    unsigned int* cnt = (unsigned int*)(ws + OFF_CNT);
    _Float16* hex  = (_Float16*)(ws + OFF_HEX);
    _Float16* WihT = (_Float16*)(ws + OFF_WIHT);
    _Float16* WhhT = (_Float16*)(ws + OFF_WHHT);
    _Float16* xp   = (_Float16*)(ws + OFF_XP);

    prep_transpose<<<dim3(16, 16, 2), 256, 0, stream>>>(Wih, Whh, WihT, WhhT);
    zero_cnt<<<32, 256, 0, stream>>>(cnt);
    xp_gemm<<<dim3(4, 1024), 256, 0, stream>>>(x, WihT, xp);
    rnn_scan<<<64, 256, 0, stream>>>(xp, WhhT, b, hex, cnt, out);
}

// Round 2
// 4558.376 us; speedup vs baseline: 1.5289x; 1.5289x over previous
//
#include <hip/hip_runtime.h>
#include <hip/hip_fp16.h>

typedef _Float16 half8 __attribute__((ext_vector_type(8)));
typedef _Float16 half4v __attribute__((ext_vector_type(4)));
typedef float floatx4 __attribute__((ext_vector_type(4)));

constexpr int BN = 128;    // batch
constexpr int T  = 1024;   // time steps
constexpr int D  = 512;    // input dim
constexpr int H  = 512;    // hidden dim

// Workspace layout (bytes)
constexpr size_t OFF_WIHT = 0;                    // W_ih^T f16 = 512 KB
constexpr size_t OFF_WHHT = 524288;               // W_hh^T f16 = 512 KB
constexpr size_t OFF_XP   = 2097152;              // xp f16 [T][B][H] = 128 MB

__device__ __forceinline__ float fast_tanh(float x) {
    float e = __expf(2.0f * x);
    return 1.0f - 2.0f / (e + 1.0f);
}

// ---------------------------------------------------------------------------
// Prep: transpose 512x512 fp32 -> fp16 (row-major [n][k] = W[k][n])
// ---------------------------------------------------------------------------
__global__ __launch_bounds__(256) void prep_transpose(
    const float* __restrict__ Wih, const float* __restrict__ Whh,
    _Float16* __restrict__ WihT, _Float16* __restrict__ WhhT)
{
    __shared__ float tile[32][33];
    const float* src = (blockIdx.z == 0) ? Wih : Whh;
    _Float16* dst    = (blockIdx.z == 0) ? WihT : WhhT;
    const int tx = threadIdx.x & 31;
    const int ty = threadIdx.x >> 5;
    const int kbase = blockIdx.y * 32;
    const int nbase = blockIdx.x * 32;
    for (int r = 0; r < 4; ++r)
        tile[ty + r * 8][tx] = src[(size_t)(kbase + ty + r * 8) * 512 + nbase + tx];
    __syncthreads();
    for (int r = 0; r < 4; ++r)
        dst[(size_t)(nbase + ty + r * 8) * 512 + kbase + tx] =
            (_Float16)tile[tx][ty + r * 8];
}

// ---------------------------------------------------------------------------
// Phase 1: xp[t][b][n] = x[b][t][:] @ W_ih + bias   (fp16 out, bias folded)
// grid: (N/128=4, M/128=1024), block 256 (4 waves, 2x2 of 64x64)
// ---------------------------------------------------------------------------
__global__ __launch_bounds__(256) void xp_gemm(
    const float* __restrict__ x, const _Float16* __restrict__ WT,
    const float* __restrict__ bias, _Float16* __restrict__ xp)
{
    __shared__ _Float16 As[128][40];
    __shared__ _Float16 Bs[128][40];
    const int tid  = threadIdx.x;
    const int lane = tid & 63;
    const int w    = tid >> 6;
    const int wm   = w & 1, wn = w >> 1;
    const int l15  = lane & 15, q = lane >> 4;
    const size_t mbase = (size_t)blockIdx.y * 128;
    const int    nbase = blockIdx.x * 128;

    floatx4 acc[4][4];
    for (int i = 0; i < 4; ++i)
        for (int j = 0; j < 4; ++j)
            acc[i][j] = (floatx4){0.f, 0.f, 0.f, 0.f};

    for (int kt = 0; kt < 16; ++kt) {
        const int k0 = kt * 32;
        {
            const int k4 = (tid & 7) * 4;
            const int row0 = tid >> 3;
            for (int r = 0; r < 4; ++r) {
                const int row = row0 + r * 32;
                const float4 v = *(const float4*)&x[(mbase + row) * D + k0 + k4];
                half4v hv;
                hv[0] = (_Float16)v.x; hv[1] = (_Float16)v.y;
                hv[2] = (_Float16)v.z; hv[3] = (_Float16)v.w;
                *(half4v*)&As[row][k4] = hv;
            }
        }
        {
            const int k8 = (tid & 3) * 8;
            const int n0 = tid >> 2;
            for (int r = 0; r < 2; ++r) {
                const int n = n0 + r * 64;
                *(half8*)&Bs[n][k8] =
                    *(const half8*)&WT[(size_t)(nbase + n) * D + k0 + k8];
            }
        }
        __syncthreads();
        half8 a[4], b[4];
        for (int i = 0; i < 4; ++i)
            a[i] = *(const half8*)&As[wm * 64 + i * 16 + l15][q * 8];
        for (int j = 0; j < 4; ++j)
            b[j] = *(const half8*)&Bs[wn * 64 + j * 16 + l15][q * 8];
        for (int i = 0; i < 4; ++i)
            for (int j = 0; j < 4; ++j)
                acc[i][j] = __builtin_amdgcn_mfma_f32_16x16x32_f16(
                    a[i], b[j], acc[i][j], 0, 0, 0);
        __syncthreads();
    }
    // epilogue: C/D layout col=lane&15, row=q*4+reg. Output to xp[t][b][col],
    // with row = b*T + t. Bias folded in here.
    float bc[4];
    for (int j = 0; j < 4; ++j)
        bc[j] = bias[nbase + wn * 64 + j * 16 + l15];
    for (int i = 0; i < 4; ++i)
        for (int r = 0; r < 4; ++r) {
            const size_t row = mbase + wm * 64 + i * 16 + q * 4 + r;
            const int b_row = (int)(row >> 10);      // T = 1024
            const int tt    = (int)(row & 1023);
            _Float16* dst = &xp[((size_t)tt * BN + b_row) * H];
            for (int j = 0; j < 4; ++j) {
                const int col = nbase + wn * 64 + j * 16 + l15;
                dst[col] = (_Float16)(acc[i][j][r] + bc[j]);
            }
        }
}

// ---------------------------------------------------------------------------
// Phase 2: sequential scan, ZERO inter-WG sync. 8 WGs x 512 threads; WG g owns
// batch rows [g*16, g*16+16). Wave w owns hidden cols [w*64, w*64+64).
// MFMA roles: A = W_hh^T fragment (m = hidden col), B = h fragment (n = batch).
// h lives in LDS in MFMA-fragment-permuted layout:
//   h[batch][hid] stored at ((c*4+qr)*16 + batch)*8 + (hid&7),
//   where c = hid>>5, qr = (hid>>3)&3.
//   -> B-frag reads are linear ds_read_b128; C-writes are linear ds_write_b64.
// W k-tiles: c=0..11 in registers (192 VGPR), c=12..14 streamed from L2 each
// step (96 KB/CU/step, hidden behind reg-tile MFMAs), c=15 resident in LDS.
// ---------------------------------------------------------------------------
__global__ __launch_bounds__(512) void rnn_scan(
    const _Float16* __restrict__ xp, const _Float16* __restrict__ WT,
    float* __restrict__ out)
{
    __shared__ _Float16 hbuf[2][16 * 512];   // 32 KB, frag-permuted
    __shared__ _Float16 wlds[8 * 4 * 4 * 16 * 8]; // 32 KB, c=15 W tile, frag order

    const int g    = blockIdx.x;
    const int tid  = threadIdx.x;
    const int lane = tid & 63;
    const int w    = tid >> 6;           // wave 0..7
    const int l15  = lane & 15;
    const int q    = lane >> 4;

    // ---- init: W fragments. Row pointer for A-frag m = w*64 + i*16 + l15.
    half8 wf[4][12];
    for (int i = 0; i < 4; ++i) {
        const _Float16* wr = WT + (size_t)(w * 64 + i * 16 + l15) * H;
        for (int c = 0; c < 12; ++c)
            wf[i][c] = *(const half8*)&wr[c * 32 + q * 8];
        // c=15 tile into LDS (each wave writes/reads only its own slice)
        *(half8*)&wlds[(((w * 4 + i) * 4 + q) * 16 + l15) * 8] =
            *(const half8*)&wr[15 * 32 + q * 8];
    }

    // ---- t = 0: h1 = tanh(xp_0) (bias already folded into xp), h0 = 0.
    {
        const _Float16* x0 = xp + ((size_t)0 * BN + g * 16 + l15) * H;
        for (int i = 0; i < 4; ++i) {
            const int hid = w * 64 + i * 16 + q * 4;
            half4v v = *(const half4v*)&x0[hid];
            half4v hn;
            for (int r = 0; r < 4; ++r)
                hn[r] = (_Float16)fast_tanh((float)v[r]);
            const int c = hid >> 5, qr = (hid >> 3) & 3, lo = hid & 7;
            *(half4v*)&hbuf[1][((c * 4 + qr) * 16 + l15) * 8 + lo] = hn;
        }
        __syncthreads();
    }

    const _Float16* wrow[4];
    for (int i = 0; i < 4; ++i)
        wrow[i] = WT + (size_t)(w * 64 + i * 16 + l15) * H + q * 8;

    for (int t = 1; t < T; ++t) {
        const _Float16* hb = hbuf[t & 1];

        // prefetch this step's xp (independent of h)
        half4v xpv[4];
        {
            const _Float16* xt = xp + ((size_t)t * BN + g * 16 + l15) * H;
            for (int i = 0; i < 4; ++i)
                xpv[i] = *(const half4v*)&xt[w * 64 + i * 16 + q * 4];
        }
        // prefetch streamed W tile c=12 (L2-resident; ~2.3k cyc to hide)
        half8 s[4];
        for (int i = 0; i < 4; ++i)
            s[i] = *(const half8*)&wrow[i][12 * 32];

        floatx4 acc[4];
        for (int i = 0; i < 4; ++i) acc[i] = (floatx4){0.f, 0.f, 0.f, 0.f};

        for (int c = 0; c < 12; ++c) {
            half8 hf = *(const half8*)&hb[((c * 4 + q) * 16 + l15) * 8];
            for (int i = 0; i < 4; ++i)
                acc[i] = __builtin_amdgcn_mfma_f32_16x16x32_f16(
                    wf[i][c], hf, acc[i], 0, 0, 0);
        }
        // c = 12 (streamed), then stream 13, 14
        {
            half8 hf = *(const half8*)&hb[((12 * 4 + q) * 16 + l15) * 8];
            for (int i = 0; i < 4; ++i)
                acc[i] = __builtin_amdgcn_mfma_f32_16x16x32_f16(
                    s[i], hf, acc[i], 0, 0, 0);
        }
        for (int i = 0; i < 4; ++i) s[i] = *(const half8*)&wrow[i][13 * 32];
        {
            half8 hf = *(const half8*)&hb[((13 * 4 + q) * 16 + l15) * 8];
            for (int i = 0; i < 4; ++i)
                acc[i] = __builtin_amdgcn_mfma_f32_16x16x32_f16(
                    s[i], hf, acc[i], 0, 0, 0);
        }
        for (int i = 0; i < 4; ++i) s[i] = *(const half8*)&wrow[i][14 * 32];
        {
            half8 hf = *(const half8*)&hb[((14 * 4 + q) * 16 + l15) * 8];
            for (int i = 0; i < 4; ++i)
                acc[i] = __builtin_amdgcn_mfma_f32_16x16x32_f16(
                    s[i], hf, acc[i], 0, 0, 0);
        }
        // c = 15 from LDS
        {
            half8 hf = *(const half8*)&hb[((15 * 4 + q) * 16 + l15) * 8];
            for (int i = 0; i < 4; ++i) {
                half8 wl = *(const half8*)&wlds[(((w * 4 + i) * 4 + q) * 16 + l15) * 8];
                acc[i] = __builtin_amdgcn_mfma_f32_16x16x32_f16(
                    wl, hf, acc[i], 0, 0, 0);
            }
        }

        if (t < T - 1) {
            _Float16* ho = hbuf[(t + 1) & 1];
            for (int i = 0; i < 4; ++i) {
                const int hid = w * 64 + i * 16 + q * 4;
                half4v hn;
                for (int r = 0; r < 4; ++r)
                    hn[r] = (_Float16)fast_tanh(acc[i][r] + (float)xpv[i][r]);
                const int c = hid >> 5, qr = (hid >> 3) & 3, lo = hid & 7;
                *(half4v*)&hbuf[(t + 1) & 1][((c * 4 + qr) * 16 + l15) * 8 + lo] = hn;
            }
            __syncthreads();
        } else {
            // final step: write fp32 output directly (out[batch][hid])
            for (int i = 0; i < 4; ++i) {
                const int hid = w * 64 + i * 16 + q * 4;
                float4 o;
                o.x = fast_tanh(acc[i][0] + (float)xpv[i][0]);
                o.y = fast_tanh(acc[i][1] + (float)xpv[i][1]);
                o.z = fast_tanh(acc[i][2] + (float)xpv[i][2]);
                o.w = fast_tanh(acc[i][3] + (float)xpv[i][3]);
                *(float4*)&out[(size_t)(g * 16 + l15) * H + hid] = o;
            }
        }
    }
}

// ---------------------------------------------------------------------------
extern "C" void kernel_launch(void* const* d_in, const int* in_sizes, int n_in,
                              void* d_out, int out_size, void* d_ws, size_t ws_size,
                              hipStream_t stream)
{
    const float* x   = (const float*)d_in[0];
    const float* Wih = (const float*)d_in[1];
    const float* Whh = (const float*)d_in[2];
    const float* b   = (const float*)d_in[3];
    float* out = (float*)d_out;

    char* ws = (char*)d_ws;
    _Float16* WihT = (_Float16*)(ws + OFF_WIHT);
    _Float16* WhhT = (_Float16*)(ws + OFF_WHHT);
    _Float16* xp   = (_Float16*)(ws + OFF_XP);

    prep_transpose<<<dim3(16, 16, 2), 256, 0, stream>>>(Wih, Whh, WihT, WhhT);
    xp_gemm<<<dim3(4, 1024), 256, 0, stream>>>(x, WihT, b, xp);
    rnn_scan<<<8, 512, 0, stream>>>(xp, WhhT, out);
}